// Round 1
// baseline (80.546 us; speedup 1.0000x reference)
//
#include <hip/hip_runtime.h>

#define IN_FEATURES 4096
#define OUT_FEATURES 11008
#define KW (IN_FEATURES / 8)     // 512 packed words along input dim
#define BLOCK 256
#define O_PER_BLOCK 32           // outputs per block
#define KG 32                    // k-slices per block (threads along k)
#define W_PER_THREAD (KW / KG)   // 16 words per thread

__global__ __launch_bounds__(BLOCK) void quant4_matvec(
    const float* __restrict__ x,
    const int* __restrict__ qw,
    const float* __restrict__ scales,
    const float* __restrict__ zeros,
    const float* __restrict__ bias,
    float* __restrict__ out)
{
    __shared__ float xs[IN_FEATURES];          // 16 KB staged x
    __shared__ float red[KG][O_PER_BLOCK];     // 4 KB partial sums
    __shared__ float xsum_s[BLOCK / 64];

    const int tid = threadIdx.x;

    // ---- stage x into LDS (float4, coalesced) and compute block-wide x_sum ----
    float xpart = 0.f;
    const float4* x4 = (const float4*)x;
    float4* xs4 = (float4*)xs;
#pragma unroll
    for (int i = 0; i < IN_FEATURES / 4 / BLOCK; ++i) {   // 4 iterations
        float4 v = x4[i * BLOCK + tid];
        xs4[i * BLOCK + tid] = v;
        xpart += v.x + v.y + v.z + v.w;
    }
#pragma unroll
    for (int off = 32; off > 0; off >>= 1)
        xpart += __shfl_down(xpart, off);
    if ((tid & 63) == 0) xsum_s[tid >> 6] = xpart;
    __syncthreads();

    // ---- main loop: each thread = 4 consecutive outputs x 16 k-words ----
    const int og = tid & 7;        // output group (4 outputs each) within block
    const int kg = tid >> 3;       // k-slice 0..31
    const int o_base = blockIdx.x * O_PER_BLOCK;
    const int o4 = o_base + og * 4;

    float acc0 = 0.f, acc1 = 0.f, acc2 = 0.f, acc3 = 0.f;
#pragma unroll
    for (int w = 0; w < W_PER_THREAD; ++w) {
        const int k = w * KG + kg;                         // strided: 2-way LDS alias (free)
        const int4 q = *(const int4*)(qw + k * OUT_FEATURES + o4);  // 16B coalesced
        const float4 xa = *(const float4*)(&xs[k * 8]);
        const float4 xb = *(const float4*)(&xs[k * 8 + 4]);
        const float xv[8] = {xa.x, xa.y, xa.z, xa.w, xb.x, xb.y, xb.z, xb.w};
        const unsigned qx = (unsigned)q.x, qy = (unsigned)q.y,
                       qz = (unsigned)q.z, qw_ = (unsigned)q.w;
#pragma unroll
        for (int n = 0; n < 8; ++n) {
            const float xvn = xv[n];
            acc0 += xvn * (float)((qx >> (4 * n)) & 0xFu);
            acc1 += xvn * (float)((qy >> (4 * n)) & 0xFu);
            acc2 += xvn * (float)((qz >> (4 * n)) & 0xFu);
            acc3 += xvn * (float)((qw_ >> (4 * n)) & 0xFu);
        }
    }

    // ---- reduce across k-slices ----
    red[kg][og * 4 + 0] = acc0;
    red[kg][og * 4 + 1] = acc1;
    red[kg][og * 4 + 2] = acc2;
    red[kg][og * 4 + 3] = acc3;
    __syncthreads();

    if (tid < O_PER_BLOCK) {
        float s = 0.f;
#pragma unroll
        for (int g = 0; g < KG; ++g) s += red[g][tid];
        const float xsum = xsum_s[0] + xsum_s[1] + xsum_s[2] + xsum_s[3];
        const int o = o_base + tid;
        out[o] = s * scales[o] - xsum * zeros[o] + bias[o];
    }
}

extern "C" void kernel_launch(void* const* d_in, const int* in_sizes, int n_in,
                              void* d_out, int out_size, void* d_ws, size_t ws_size,
                              hipStream_t stream) {
    const float* x      = (const float*)d_in[0];
    const int*   qw     = (const int*)d_in[1];
    const float* scales = (const float*)d_in[2];
    const float* zeros  = (const float*)d_in[3];
    const float* bias   = (const float*)d_in[4];
    float* out = (float*)d_out;

    const int grid = OUT_FEATURES / O_PER_BLOCK;  // 344
    quant4_matvec<<<grid, BLOCK, 0, stream>>>(x, qw, scales, zeros, bias, out);
}

// Round 2
// 79.720 us; speedup vs baseline: 1.0104x; 1.0104x over previous
//
#include <hip/hip_runtime.h>

#define IN_FEATURES 4096
#define OUT_FEATURES 11008
#define KW (IN_FEATURES / 8)     // 512 packed words along input dim
#define SPLIT 4                  // k-split across blocks
#define KWB (KW / SPLIT)         // 128 words per block slice
#define BLOCK 256
#define OPB 32                   // outputs per block (128 B contiguous -> full-line coalescing)
#define KG 32                    // k-slices per block
#define W (KWB / KG)             // 4 words per thread (4 independent loads in flight)
#define NWAVE (BLOCK / 64)

__global__ __launch_bounds__(BLOCK) void quant4_matvec_split(
    const float* __restrict__ x,
    const int* __restrict__ qw,
    const float* __restrict__ scales,
    const float* __restrict__ zeros,
    const float* __restrict__ bias,
    float* __restrict__ out)
{
    __shared__ float xs[KWB * 8];        // 4 KB: this block's x slice
    __shared__ float red[NWAVE][OPB];    // per-wave partials
    __shared__ float xsum_s[NWAVE];

    const int tid = threadIdx.x;
    const int ob  = blockIdx.x;          // output tile 0..343
    const int q   = blockIdx.y;          // k-split slice 0..3

    // ---- stage this k-slice of x into LDS; compute slice x-sum ----
    const float4* x4 = (const float4*)x;
    float4 v = x4[q * (KWB * 2) + tid];  // KWB*8/4 = 256 float4 per slice
    ((float4*)xs)[tid] = v;
    float xpart = v.x + v.y + v.z + v.w;
#pragma unroll
    for (int off = 32; off > 0; off >>= 1)
        xpart += __shfl_down(xpart, off);
    if ((tid & 63) == 0) xsum_s[tid >> 6] = xpart;
    __syncthreads();

    // ---- each thread: 4 consecutive outputs x 4 k-words (independent loads) ----
    const int og = tid & 7;              // 8 output groups of 4
    const int kg = tid >> 3;             // k-slice 0..31 within block
    const int o4 = ob * OPB + og * 4;

    float acc0 = 0.f, acc1 = 0.f, acc2 = 0.f, acc3 = 0.f;
#pragma unroll
    for (int w = 0; w < W; ++w) {
        const int kl = w * KG + kg;                  // local row; banks: 2-way alias (free)
        const int krow = q * KWB + kl;               // global packed row
        const int4 qv = *(const int4*)(qw + (long)krow * OUT_FEATURES + o4);
        const float4 xa = *(const float4*)(&xs[kl * 8]);
        const float4 xb = *(const float4*)(&xs[kl * 8 + 4]);
        const float xv[8] = {xa.x, xa.y, xa.z, xa.w, xb.x, xb.y, xb.z, xb.w};
        const unsigned qx = (unsigned)qv.x, qy = (unsigned)qv.y,
                       qz = (unsigned)qv.z, qwv = (unsigned)qv.w;
#pragma unroll
        for (int n = 0; n < 8; ++n) {
            const float xvn = xv[n];
            acc0 += xvn * (float)((qx >> (4 * n)) & 0xFu);
            acc1 += xvn * (float)((qy >> (4 * n)) & 0xFu);
            acc2 += xvn * (float)((qz >> (4 * n)) & 0xFu);
            acc3 += xvn * (float)((qwv >> (4 * n)) & 0xFu);
        }
    }

    // ---- wave-level butterfly over the 8 k-groups within each wave ----
    // lane = kg(low 3 bits of tid>>3 ... ) : lanes differing in bits 3..5 share og
#pragma unroll
    for (int m = 8; m <= 32; m <<= 1) {
        acc0 += __shfl_xor(acc0, m);
        acc1 += __shfl_xor(acc1, m);
        acc2 += __shfl_xor(acc2, m);
        acc3 += __shfl_xor(acc3, m);
    }
    const int lane = tid & 63;
    const int wid  = tid >> 6;
    if (lane < 8) {                      // lane == og here
        red[wid][lane * 4 + 0] = acc0;
        red[wid][lane * 4 + 1] = acc1;
        red[wid][lane * 4 + 2] = acc2;
        red[wid][lane * 4 + 3] = acc3;
    }
    __syncthreads();

    // ---- combine waves, apply distributed epilogue, atomic into out ----
    if (tid < OPB) {
        float s = 0.f;
#pragma unroll
        for (int g = 0; g < NWAVE; ++g) s += red[g][tid];
        float xsumq = 0.f;
#pragma unroll
        for (int g = 0; g < NWAVE; ++g) xsumq += xsum_s[g];
        const int o = ob * OPB + tid;
        float val = s * scales[o] - xsumq * zeros[o];
        if (q == 0) val += bias[o];
        atomicAdd(out + o, val);
    }
}

extern "C" void kernel_launch(void* const* d_in, const int* in_sizes, int n_in,
                              void* d_out, int out_size, void* d_ws, size_t ws_size,
                              hipStream_t stream) {
    const float* x      = (const float*)d_in[0];
    const int*   qw     = (const int*)d_in[1];
    const float* scales = (const float*)d_in[2];
    const float* zeros  = (const float*)d_in[3];
    const float* bias   = (const float*)d_in[4];
    float* out = (float*)d_out;

    hipMemsetAsync(out, 0, OUT_FEATURES * sizeof(float), stream);

    dim3 grid(OUT_FEATURES / OPB, SPLIT);   // 344 x 4 = 1376 blocks
    quant4_matvec_split<<<grid, BLOCK, 0, stream>>>(x, qw, scales, zeros, bias, out);
}